// Round 2
// baseline (288.020 us; speedup 1.0000x reference)
//
#include <hip/hip_runtime.h>
#include <math.h>

typedef unsigned int uint;
typedef unsigned short ushort;
typedef unsigned char uchar;
typedef unsigned long ulong_;
typedef __attribute__((ext_vector_type(4))) float f32x4;

// Problem constants
#define BB  16384
#define DD  64
#define NT_ 128
#define NZ_ 2048
#define NJ_ 2049   // NZ+1

// workspace layout (float offsets)
#define FLAG_OFF 0         // 2 uint barrier counters (+pad), memset to 0 per launch
#define BIAS_OFF 16        // fp32 [64]
#define SCS_OFF  80        // float4 [2048] = {cc, inv, q, inv*log2e}
#define CZ8A_OFF 8272      // fp8 cz k0 [NZ][32]
#define CZ8B_OFF 24656     // fp8 cz k1 [NZ][32]
#define WZ8A_OFF 41040     // fp8 WzT k0 [NZ][32]
#define WZ8B_OFF 57424     // fp8 WzT k1 [NZ][32]
#define WZBP_OFF 73808     // fp8 Wz packed [64 chunks][64 d][32 c]
#define WT_OFF   106576    // fp32 W_t [64][NJ_] (bias col unused)
// end 237712 floats ~= 0.95 MB

// ---------------- fp8 e4m3 (OCP) conversion helpers ----------------
#if __has_builtin(__builtin_amdgcn_cvt_pk_fp8_f32)
__device__ __forceinline__ uint pk4_fp8(float a, float b, float c, float d) {
  int v = __builtin_amdgcn_cvt_pk_fp8_f32(a, b, 0, false);
  v = __builtin_amdgcn_cvt_pk_fp8_f32(c, d, v, true);
  return (uint)v;
}
__device__ __forceinline__ uchar f8_1(float x) {
  return (uchar)(__builtin_amdgcn_cvt_pk_fp8_f32(x, x, 0, false) & 0xFF);
}
#else
__device__ __forceinline__ uint sw_f8(float x) {
  uint u = __float_as_uint(x);
  uint s = (u >> 24) & 0x80u;
  float ax = __uint_as_float(u & 0x7FFFFFFFu);
  if (!(ax >= 0.015625f)) return s;          // flush tiny / NaN -> signed zero
  if (ax >= 448.f) return s | 0x7Eu;
  uint q = __float_as_uint(ax);
  q += 0x7FFFFu + ((q >> 20) & 1u);          // RNE at mantissa bit 20
  uint e = (q >> 23) - 120u;                 // rebias (127 -> 7)
  return s | ((e & 0xFu) << 3) | ((q >> 20) & 7u);
}
__device__ __forceinline__ uchar f8_1(float x) { return (uchar)sw_f8(x); }
__device__ __forceinline__ uint pk4_fp8(float a, float b, float c, float d) {
  return sw_f8(a) | (sw_f8(b) << 8) | (sw_f8(c) << 16) | (sw_f8(d) << 24);
}
#endif

// ---------------------------------------------------------------------------
// Single fused kernel. Grid 512 x 256 thr. __launch_bounds__(256,2) caps VGPR
// at 256 -> 2 blocks/CU -> all 512 blocks co-resident -> grid barriers are
// deadlock-free. Barrier counters are zeroed by a memset node in the same
// graph, so they are correct on every execution regardless of workspace
// poison or replay.
#define PH_LD 40   // bytes per phi row (32 + 8 pad)

__global__ __launch_bounds__(256, 2) void k_all(
    const float* __restrict__ t, const float* __restrict__ z,
    const float* __restrict__ cz, const float* __restrict__ lsz,
    const float* __restrict__ ct, const float* __restrict__ lst,
    const float* __restrict__ W,
    uint* __restrict__ flags, float* __restrict__ bias,
    float4* __restrict__ scs,
    uchar* __restrict__ cz8a, uchar* __restrict__ cz8b,
    uchar* __restrict__ wz8a, uchar* __restrict__ wz8b,
    uchar* __restrict__ wzbp8, float* __restrict__ wt32,
    float* __restrict__ out)
{
  __shared__ char smem[10240];   // phi-fp8 [2][4][32][PH_LD]  OR  eps [32][68] f32
  __shared__ float dlr[4][32];
  __shared__ float phi_t[NT_];
  __shared__ float bred[2];
  uchar* phs = (uchar*)smem;
  float* eps = (float*)smem;

  int tid  = threadIdx.x;
  int bid  = blockIdx.x;
  int wsp  = tid >> 6;           // wave = c-split group 0..3
  int lane = tid & 63;
  int lrow = lane & 15, quad = lane >> 4;
  int b0 = bid * 32;

  // ==== Phase C prologue (independent of W): z -> fp8 A-frags + row norms ===
  long az[2][2];
  float zzr[2][4];
#pragma unroll
  for (int mt = 0; mt < 2; ++mt) {
    const float* zr = z + (size_t)(b0 + mt * 16 + lrow) * DD + quad * 8;
    float4 v0 = *(const float4*)zr;
    float4 v1 = *(const float4*)(zr + 4);
    float4 v2 = *(const float4*)(zr + 32);
    float4 v3 = *(const float4*)(zr + 36);
    uint l0 = pk4_fp8(v0.x, v0.y, v0.z, v0.w);
    uint l1 = pk4_fp8(v1.x, v1.y, v1.z, v1.w);
    uint h0 = pk4_fp8(v2.x, v2.y, v2.z, v2.w);
    uint h1 = pk4_fp8(v3.x, v3.y, v3.z, v3.w);
    az[mt][0] = (long)(((ulong_)l1 << 32) | l0);
    az[mt][1] = (long)(((ulong_)h1 << 32) | h0);
    float ss = v0.x * v0.x + v0.y * v0.y + v0.z * v0.z + v0.w * v0.w
             + v1.x * v1.x + v1.y * v1.y + v1.z * v1.z + v1.w * v1.w
             + v2.x * v2.x + v2.y * v2.y + v2.z * v2.z + v2.w * v2.w
             + v3.x * v3.x + v3.y * v3.y + v3.z * v3.z + v3.w * v3.w;
    ss += __shfl_xor(ss, 16);
    ss += __shfl_xor(ss, 32);
#pragma unroll
    for (int i = 0; i < 4; ++i) zzr[mt][i] = __shfl(ss, quad * 4 + i);
  }

  // ==== Phase A: W_t for (d = bid>>3, j-chunk bid&7), fp8 packs, cz8, scs ===
  int dA = bid >> 3, jblk = bid & 7;
  if (tid < NT_) {
    float r = fabsf(t[0] - ct[tid]) * __expf(-lst[tid]);
    phi_t[tid] = __expf(-r * r);
  }
  __syncthreads();
  {
    int j = jblk * 256 + tid;    // 0..2047
    const float* Wp = W + (size_t)dA * NT_ * NJ_ + j;
    float acc = 0.f;
#pragma unroll 16
    for (int k = 0; k < NT_; ++k) acc += Wp[(size_t)k * NJ_] * phi_t[k];
    wt32[(size_t)dA * NJ_ + j] = acc;
    uchar a8 = f8_1(acc);
    wzbp8[(size_t)(j >> 5) * 2048 + dA * 32 + (j & 31)] = a8;
    if (dA < 32) wz8a[(size_t)j * 32 + dA] = a8;
    else         wz8b[(size_t)j * 32 + (dA - 32)] = a8;
  }
  // bias[dA] = sum_k W[dA][k][2048]*phi[k]  (jblk==0 blocks only)
  {
    float bv = 0.f;
    if (jblk == 0 && tid < NT_)
      bv = W[(size_t)dA * NT_ * NJ_ + (size_t)tid * NJ_ + 2048] * phi_t[tid];
    bv += __shfl_xor(bv, 1);
    bv += __shfl_xor(bv, 2);
    bv += __shfl_xor(bv, 4);
    bv += __shfl_xor(bv, 8);
    bv += __shfl_xor(bv, 16);
    bv += __shfl_xor(bv, 32);
    if (jblk == 0 && tid < NT_ && lane == 0) bred[tid >> 6] = bv;
  }
  // cz8 pack + scs {cc, inv, 0, inv*log2e}: 4 centres/block, 1 wave/centre
  {
    int c = bid * 4 + wsp;
    float v = cz[(size_t)c * DD + lane];
    uchar c8 = f8_1(v);
    if (lane < 32) cz8a[(size_t)c * 32 + lane] = c8;
    else           cz8b[(size_t)c * 32 + (lane - 32)] = c8;
    float ss = v * v;
    ss += __shfl_xor(ss, 1);
    ss += __shfl_xor(ss, 2);
    ss += __shfl_xor(ss, 4);
    ss += __shfl_xor(ss, 8);
    ss += __shfl_xor(ss, 16);
    ss += __shfl_xor(ss, 32);
    if (lane == 0) {
      float inv = __expf(-2.f * lsz[c]);
      scs[c] = make_float4(ss, inv, 0.f, inv * 1.44269504f);
    }
  }
  __syncthreads();
  if (jblk == 0 && tid == 0) bias[dA] = bred[0] + bred[1];

  // ==== grid barrier 1 (all W_t written) ====
  __threadfence();
  if (tid == 0) {
    atomicAdd(&flags[0], 1u);
    while (__hip_atomic_load(&flags[0], __ATOMIC_ACQUIRE,
                             __HIP_MEMORY_SCOPE_AGENT) < 512u)
      __builtin_amdgcn_s_sleep(2);
  }
  __syncthreads();

  // ==== Phase B: q[c] = sum_d W_t[d][c]*cz[c][d] (needs all d) ====
  {
    int c = bid * 4 + wsp;
    float qv = wt32[(size_t)lane * NJ_ + c] * cz[(size_t)c * DD + lane];
    qv += __shfl_xor(qv, 1);
    qv += __shfl_xor(qv, 2);
    qv += __shfl_xor(qv, 4);
    qv += __shfl_xor(qv, 8);
    qv += __shfl_xor(qv, 16);
    qv += __shfl_xor(qv, 32);
    if (lane == 0) ((float*)&scs[c])[2] = qv;   // scs[c].z
  }

  // ==== grid barrier 2 (scs complete) ====
  __threadfence();
  if (tid == 0) {
    atomicAdd(&flags[1], 1u);
    while (__hip_atomic_load(&flags[1], __ATOMIC_ACQUIRE,
                             __HIP_MEMORY_SCOPE_AGENT) < 512u)
      __builtin_amdgcn_s_sleep(2);
  }
  __syncthreads();

  // ==== Phase C: fused fp8 MFMA main loop (proven body, unchanged) ====
  f32x4 acc[2][4];
#pragma unroll
  for (int mt = 0; mt < 2; ++mt)
#pragma unroll
    for (int nt = 0; nt < 4; ++nt) acc[mt][nt] = (f32x4){0.f, 0.f, 0.f, 0.f};
  float dl[2][4] = {{0.f}};

  const f32x4 zero = (f32x4){0.f, 0.f, 0.f, 0.f};
  int cbase = wsp * 512;
  int pbase = wsp * 32 * PH_LD;   // within one parity bank

  long Abc0[2][2], Abc1[2][2], Abw0[2][2], Abw1[2][2], Abb[2][4];
  float4 Asc[2][2];
#define LOADB(PAR, C0)                                                         \
  do {                                                                         \
    int c0_ = (C0);                                                            \
    _Pragma("unroll")                                                          \
    for (int nt = 0; nt < 2; ++nt) {                                           \
      int cg_ = c0_ + nt * 16 + lrow;                                          \
      size_t ro_ = (size_t)cg_ * 32 + quad * 8;                                \
      Abc0[PAR][nt] = *(const long*)(cz8a + ro_);                              \
      Abc1[PAR][nt] = *(const long*)(cz8b + ro_);                              \
      Abw0[PAR][nt] = *(const long*)(wz8a + ro_);                              \
      Abw1[PAR][nt] = *(const long*)(wz8b + ro_);                              \
      Asc[PAR][nt]  = scs[cg_];                                                \
    }                                                                          \
    size_t cb_ = (size_t)(c0_ >> 5) * 64 * 32;                                 \
    _Pragma("unroll")                                                          \
    for (int nt = 0; nt < 4; ++nt)                                             \
      Abb[PAR][nt] =                                                           \
          *(const long*)(wzbp8 + cb_ + (size_t)(nt * 16 + lrow) * 32 + quad * 8); \
  } while (0)

  LOADB(0, cbase);
#pragma unroll 2
  for (int it = 0; it < 16; ++it) {
    int par = it & 1;
    LOADB(par ^ 1, cbase + ((it + 1) & 15) * 32);

    int pb = par * (4 * 32 * PH_LD) + pbase;
    // ---- GEMM1 + elementwise (2 n-tiles of 16 centres) ----
#pragma unroll
    for (int nt = 0; nt < 2; ++nt) {
      float4 sc = Asc[par][nt];       // {cc, inv, q, inv*log2e}
#pragma unroll
      for (int mt = 0; mt < 2; ++mt) {
        f32x4 d1 = __builtin_amdgcn_mfma_f32_16x16x32_fp8_fp8(az[mt][0], Abc0[par][nt], zero, 0, 0, 0);
        d1       = __builtin_amdgcn_mfma_f32_16x16x32_fp8_fp8(az[mt][1], Abc1[par][nt], d1,   0, 0, 0);
        f32x4 d2 = __builtin_amdgcn_mfma_f32_16x16x32_fp8_fp8(az[mt][0], Abw0[par][nt], zero, 0, 0, 0);
        d2       = __builtin_amdgcn_mfma_f32_16x16x32_fp8_fp8(az[mt][1], Abw1[par][nt], d2,   0, 0, 0);
#pragma unroll
        for (int i = 0; i < 4; ++i) {
          float e = fmaf(d1[i], 2.f, -(zzr[mt][i] + sc.x)) * sc.w;
          e = fminf(e, 0.f);
          float p;
          asm("v_exp_f32 %0, %1" : "=v"(p) : "v"(e));
          dl[mt][i] += p * sc.y * (d2[i] - sc.z);
          phs[pb + (mt * 16 + quad * 4 + i) * PH_LD + nt * 16 + lrow] = f8_1(p);
        }
      }
    }
    // ---- GEMM2: dz += phi @ Wz ----
    long ap0 = *(const long*)&phs[pb + lrow * PH_LD + quad * 8];
    long ap1 = *(const long*)&phs[pb + (16 + lrow) * PH_LD + quad * 8];
    __builtin_amdgcn_s_setprio(1);
#pragma unroll
    for (int nt = 0; nt < 4; ++nt) {
      acc[0][nt] = __builtin_amdgcn_mfma_f32_16x16x32_fp8_fp8(ap0, Abb[par][nt], acc[0][nt], 0, 0, 0);
      acc[1][nt] = __builtin_amdgcn_mfma_f32_16x16x32_fp8_fp8(ap1, Abb[par][nt], acc[1][nt], 0, 0, 0);
    }
    __builtin_amdgcn_s_setprio(0);
  }
#undef LOADB

  // ---- dl partials ----
#pragma unroll
  for (int mt = 0; mt < 2; ++mt)
#pragma unroll
    for (int i = 0; i < 4; ++i) {
      float v = dl[mt][i];
      v += __shfl_xor(v, 1);
      v += __shfl_xor(v, 2);
      v += __shfl_xor(v, 4);
      v += __shfl_xor(v, 8);
      if (lrow == 0) dlr[wsp][mt * 16 + quad * 4 + i] = v;
    }

  // ---- dz combine across the 4 c-split waves (eps reuses phi LDS) ----
  for (int s = 0; s < 4; ++s) {
    __syncthreads();
    if (wsp == s) {
#pragma unroll
      for (int mt = 0; mt < 2; ++mt)
#pragma unroll
        for (int nt = 0; nt < 4; ++nt)
#pragma unroll
          for (int i = 0; i < 4; ++i) {
            int r = mt * 16 + quad * 4 + i;
            int dd = nt * 16 + lrow;
            if (s == 0) eps[r * 68 + dd] = acc[mt][nt][i];
            else        eps[r * 68 + dd] += acc[mt][nt][i];
          }
    }
  }
  __syncthreads();

  // ---- outputs ----
  {
    int r = tid >> 3, d0 = (tid & 7) * 8;   // 256 thr x 8 floats = 32x64
    float4 e0 = *(const float4*)&eps[r * 68 + d0];
    float4 e1 = *(const float4*)&eps[r * 68 + d0 + 4];
    float4 bv0 = *(const float4*)&bias[d0];
    float4 bv1 = *(const float4*)&bias[d0 + 4];
    float4 o0, o1;
    o0.x = e0.x + bv0.x; o0.y = e0.y + bv0.y; o0.z = e0.z + bv0.z; o0.w = e0.w + bv0.w;
    o1.x = e1.x + bv1.x; o1.y = e1.y + bv1.y; o1.z = e1.z + bv1.z; o1.w = e1.w + bv1.w;
    *(float4*)&out[(size_t)(b0 + r) * DD + d0]     = o0;
    *(float4*)&out[(size_t)(b0 + r) * DD + d0 + 4] = o1;
  }
  if (tid < 32) {
    float s = dlr[0][tid] + dlr[1][tid] + dlr[2][tid] + dlr[3][tid];
    out[(size_t)BB * DD + b0 + tid] = 2.f * s;
  }
}

// ---------------------------------------------------------------------------
extern "C" void kernel_launch(void* const* d_in, const int* in_sizes, int n_in,
                              void* d_out, int out_size, void* d_ws, size_t ws_size,
                              hipStream_t stream)
{
  const float* t   = (const float*)d_in[0];
  const float* z   = (const float*)d_in[1];
  // d_in[2] = logp_z (unused)
  const float* cz  = (const float*)d_in[3];
  const float* lsz = (const float*)d_in[4];
  const float* ct  = (const float*)d_in[5];
  const float* lst = (const float*)d_in[6];
  const float* W   = (const float*)d_in[7];
  float* out = (float*)d_out;
  float* ws  = (float*)d_ws;

  uint*   flags = (uint*)(ws + FLAG_OFF);
  float*  bias  = ws + BIAS_OFF;
  float4* scs   = (float4*)(ws + SCS_OFF);
  uchar*  cz8a  = (uchar*)(ws + CZ8A_OFF);
  uchar*  cz8b  = (uchar*)(ws + CZ8B_OFF);
  uchar*  wz8a  = (uchar*)(ws + WZ8A_OFF);
  uchar*  wz8b  = (uchar*)(ws + WZ8B_OFF);
  uchar*  wzbp8 = (uchar*)(ws + WZBP_OFF);
  float*  wt32  = ws + WT_OFF;

  // zero the barrier counters inside the graph -> correct on every execution
  hipMemsetAsync((void*)flags, 0, 16, stream);
  k_all<<<dim3(512), 256, 0, stream>>>(t, z, cz, lsz, ct, lst, W,
                                       flags, bias, scs,
                                       cz8a, cz8b, wz8a, wz8b, wzbp8, wt32, out);
}

// Round 4
// 158.003 us; speedup vs baseline: 1.8229x; 1.8229x over previous
//
#include <hip/hip_runtime.h>
#include <math.h>

typedef unsigned int uint;
typedef unsigned short ushort;
typedef unsigned char uchar;
typedef unsigned long ulong_;
typedef __attribute__((ext_vector_type(4))) float f32x4;

// Problem constants
#define BB  16384
#define DD  64
#define NT_ 128
#define NZ_ 2048
#define NJ_ 2049   // NZ+1

// workspace layout (float offsets)
#define BIAS_OFF 0         // fp32 [64]
#define SCS_OFF  64        // float4 [2048] = {cc, inv, q, inv*log2e}
#define CZ8A_OFF 8256      // fp8 cz k0 [NZ][32]
#define CZ8B_OFF 24640     // fp8 cz k1 [NZ][32]
#define WZ8A_OFF 41024     // fp8 WzT k0 [NZ][32]
#define WZ8B_OFF 57408     // fp8 WzT k1 [NZ][32]
#define WZBP_OFF 73792     // fp8 Wz packed [64 chunks][64 d][32 c]
#define PART_OFF 106560    // fp32 partials [4][64][NJ_] = 524544
// end 631104 floats ~= 2.5 MB

// ---------------- fp8 e4m3 (OCP) conversion helpers ----------------
#if __has_builtin(__builtin_amdgcn_cvt_pk_fp8_f32)
__device__ __forceinline__ uint pk4_fp8(float a, float b, float c, float d) {
  int v = __builtin_amdgcn_cvt_pk_fp8_f32(a, b, 0, false);
  v = __builtin_amdgcn_cvt_pk_fp8_f32(c, d, v, true);
  return (uint)v;
}
__device__ __forceinline__ uchar f8_1(float x) {
  return (uchar)(__builtin_amdgcn_cvt_pk_fp8_f32(x, x, 0, false) & 0xFF);
}
#else
__device__ __forceinline__ uint sw_f8(float x) {
  uint u = __float_as_uint(x);
  uint s = (u >> 24) & 0x80u;
  float ax = __uint_as_float(u & 0x7FFFFFFFu);
  if (!(ax >= 0.015625f)) return s;          // flush tiny / NaN -> signed zero
  if (ax >= 448.f) return s | 0x7Eu;
  uint q = __float_as_uint(ax);
  q += 0x7FFFFu + ((q >> 20) & 1u);          // RNE at mantissa bit 20
  uint e = (q >> 23) - 120u;                 // rebias (127 -> 7)
  return s | ((e & 0xFu) << 3) | ((q >> 20) & 7u);
}
__device__ __forceinline__ uchar f8_1(float x) { return (uchar)sw_f8(x); }
__device__ __forceinline__ uint pk4_fp8(float a, float b, float c, float d) {
  return sw_f8(a) | (sw_f8(b) << 8) | (sw_f8(c) << 16) | (sw_f8(d) << 24);
}
#endif

// ---------------------------------------------------------------------------
// Kernel 1 (stage 1): split-K partial sums of W_t = einsum('dij,i->dj').
// 2304 blocks (9/CU, 32 waves/CU) -> latency-tolerant W read (67 MB, BW-bound).
// R2 lesson: do NOT reduce this kernel's parallelism; at 8 waves/CU the same
// read pattern collapses to ~330 GB/s.
__global__ __launch_bounds__(256) void k_wt1(
    const float* __restrict__ t, const float* __restrict__ ct,
    const float* __restrict__ lst, const float* __restrict__ W,
    float* __restrict__ part)   // [4][64][NJ_]
{
  __shared__ float ph[32];
  int tx = threadIdx.x;
  int d  = blockIdx.y;
  int ic = blockIdx.z;
  if (tx < 32) {
    int i = ic * 32 + tx;
    float r = fabsf(t[0] - ct[i]) * __expf(-lst[i]);
    ph[tx] = __expf(-r * r);
  }
  __syncthreads();
  int j = blockIdx.x * 256 + tx;
  if (j >= NJ_) return;
  const float* Wp = W + (size_t)d * NT_ * NJ_ + (size_t)(ic * 32) * NJ_ + j;
  float acc = 0.f;
#pragma unroll
  for (int k = 0; k < 32; ++k) acc += Wp[(size_t)k * NJ_] * ph[k];
  part[((size_t)ic * 64 + d) * NJ_ + j] = acc;
}

// ---------------------------------------------------------------------------
// Kernel 2 (stage 2): 256 blocks x 256 thr, 8 centres/block.
__global__ __launch_bounds__(256) void k_prep2(
    const float* __restrict__ part, const float* __restrict__ cz,
    const float* __restrict__ lsz,
    float* __restrict__ bias, float4* __restrict__ scs,
    uchar* __restrict__ cz8a, uchar* __restrict__ cz8b,
    uchar* __restrict__ wz8a, uchar* __restrict__ wz8b,
    uchar* __restrict__ wzbp8)
{
  __shared__ float wt[64][9];   // [d][c_local]
  int tid = threadIdx.x;
  int cb0 = blockIdx.x * 8;
#pragma unroll
  for (int h = 0; h < 2; ++h) {
    int f = h * 256 + tid;      // 512 = 64 d x 8 c
    int d = f >> 3, c = f & 7;
    size_t idx = (size_t)d * NJ_ + cb0 + c;
    float s = part[idx] + part[(size_t)64 * NJ_ + idx]
            + part[(size_t)128 * NJ_ + idx] + part[(size_t)192 * NJ_ + idx];
    wt[d][c] = s;
    int cg = cb0 + c;
    wzbp8[((size_t)(cg >> 5) * 64 + d) * 32 + (cg & 31)] = f8_1(s);
  }
  if (blockIdx.x == 0 && tid < 64) {
    size_t idx = (size_t)tid * NJ_ + 2048;
    bias[tid] = part[idx] + part[(size_t)64 * NJ_ + idx]
              + part[(size_t)128 * NJ_ + idx] + part[(size_t)192 * NJ_ + idx];
  }
  __syncthreads();
  int cl = tid >> 5;            // centre within block 0..7
  int k  = tid & 31;            // 0..31
  int c  = cb0 + cl;
  float cv0 = cz[(size_t)c * DD + k];
  float cv1 = cz[(size_t)c * DD + 32 + k];
  cz8a[(size_t)c * 32 + k] = f8_1(cv0);
  cz8b[(size_t)c * 32 + k] = f8_1(cv1);
  float w0 = wt[k][cl], w1 = wt[32 + k][cl];
  wz8a[(size_t)c * 32 + k] = f8_1(w0);
  wz8b[(size_t)c * 32 + k] = f8_1(w1);
  float ca = cv0 * cv0 + cv1 * cv1;
  float qa = w0 * cv0 + w1 * cv1;
  qa += __shfl_xor(qa, 1);  ca += __shfl_xor(ca, 1);
  qa += __shfl_xor(qa, 2);  ca += __shfl_xor(ca, 2);
  qa += __shfl_xor(qa, 4);  ca += __shfl_xor(ca, 4);
  qa += __shfl_xor(qa, 8);  ca += __shfl_xor(ca, 8);
  qa += __shfl_xor(qa, 16); ca += __shfl_xor(ca, 16);
  if (k == 0) {
    float inv = __expf(-2.f * lsz[c]);
    scs[c] = make_float4(ca, inv, qa, inv * 1.44269504f);
  }
}

// ---------------------------------------------------------------------------
// Main fused MFMA kernel — fp8, software-pipelined K-loop.
// BM=16: grid 1024, 4 blocks/CU (16 waves/CU, ~46% occupancy) vs the old
// BM=32/grid-512 which was grid-limited to 2 blocks/CU (23%). The inner
// GEMM1->exp->LDS->GEMM2 chain is ~60% VALU-busy per wave (R2 counters);
// doubling resident waves fills the stall slots. Tables (~450 KB) stay
// L2-resident so the doubled table re-read is cheap L2 traffic.
#define PH_LD 40   // bytes per phi row (32 + 8 pad)

__global__ __launch_bounds__(256, 4) void k_fused(
    const float* __restrict__ z,
    const uchar* __restrict__ cz8a, const uchar* __restrict__ cz8b,
    const uchar* __restrict__ wz8a, const uchar* __restrict__ wz8b,
    const uchar* __restrict__ wzbp8,
    const float4* __restrict__ scs, const float* __restrict__ bias,
    float* __restrict__ out)
{
  __shared__ char smem[5120];    // phi [2][4][16][PH_LD] fp8  OR  eps [16][68] f32
  __shared__ float dlr[4][16];
  uchar* phs = (uchar*)smem;
  float* eps = (float*)smem;

  int tid  = threadIdx.x;
  int ws   = tid >> 6;           // wave = c-split group 0..3
  int lane = tid & 63;
  int lrow = lane & 15, quad = lane >> 4;
  int b0 = blockIdx.x * 16;

  // ---- A-side prologue: read fp32 z rows, pack fp8 frags + row norms ----
  long az[2];
  float zzr[4];
  {
    const float* zr = z + (size_t)(b0 + lrow) * DD + quad * 8;
    float4 v0 = *(const float4*)zr;
    float4 v1 = *(const float4*)(zr + 4);
    float4 v2 = *(const float4*)(zr + 32);
    float4 v3 = *(const float4*)(zr + 36);
    uint l0 = pk4_fp8(v0.x, v0.y, v0.z, v0.w);
    uint l1 = pk4_fp8(v1.x, v1.y, v1.z, v1.w);
    uint h0 = pk4_fp8(v2.x, v2.y, v2.z, v2.w);
    uint h1 = pk4_fp8(v3.x, v3.y, v3.z, v3.w);
    az[0] = (long)(((ulong_)l1 << 32) | l0);
    az[1] = (long)(((ulong_)h1 << 32) | h0);
    float ss = v0.x * v0.x + v0.y * v0.y + v0.z * v0.z + v0.w * v0.w
             + v1.x * v1.x + v1.y * v1.y + v1.z * v1.z + v1.w * v1.w
             + v2.x * v2.x + v2.y * v2.y + v2.z * v2.z + v2.w * v2.w
             + v3.x * v3.x + v3.y * v3.y + v3.z * v3.z + v3.w * v3.w;
    ss += __shfl_xor(ss, 16);    // combine the 4 quad partials per row
    ss += __shfl_xor(ss, 32);
#pragma unroll
    for (int i = 0; i < 4; ++i) zzr[i] = __shfl(ss, quad * 4 + i);
  }

  f32x4 acc[4];
#pragma unroll
  for (int nt = 0; nt < 4; ++nt) acc[nt] = (f32x4){0.f, 0.f, 0.f, 0.f};
  float dl[4] = {0.f, 0.f, 0.f, 0.f};

  const f32x4 zero = (f32x4){0.f, 0.f, 0.f, 0.f};
  int cbase = ws * 512;
  int pbase = ws * 16 * PH_LD;   // within one parity bank

  // ---- register double-buffered prefetch state ----
  long Abc0[2][2], Abc1[2][2], Abw0[2][2], Abw1[2][2], Abb[2][4];
  float4 Asc[2][2];
#define LOADB(PAR, C0)                                                         \
  do {                                                                         \
    int c0_ = (C0);                                                            \
    _Pragma("unroll")                                                          \
    for (int nt = 0; nt < 2; ++nt) {                                           \
      int cg_ = c0_ + nt * 16 + lrow;                                          \
      size_t ro_ = (size_t)cg_ * 32 + quad * 8;                                \
      Abc0[PAR][nt] = *(const long*)(cz8a + ro_);                              \
      Abc1[PAR][nt] = *(const long*)(cz8b + ro_);                              \
      Abw0[PAR][nt] = *(const long*)(wz8a + ro_);                              \
      Abw1[PAR][nt] = *(const long*)(wz8b + ro_);                              \
      Asc[PAR][nt]  = scs[cg_];                                                \
    }                                                                          \
    size_t cb_ = (size_t)(c0_ >> 5) * 64 * 32;                                 \
    _Pragma("unroll")                                                          \
    for (int nt = 0; nt < 4; ++nt)                                             \
      Abb[PAR][nt] =                                                           \
          *(const long*)(wzbp8 + cb_ + (size_t)(nt * 16 + lrow) * 32 + quad * 8); \
  } while (0)

  LOADB(0, cbase);
#pragma unroll 2
  for (int it = 0; it < 16; ++it) {
    int par = it & 1;
    // prefetch next chunk (wraps to cbase on last iter -> always in-bounds)
    LOADB(par ^ 1, cbase + ((it + 1) & 15) * 32);

    int pb = par * (4 * 16 * PH_LD) + pbase;
    // ---- GEMM1 + elementwise (2 n-tiles of 16 centres) ----
#pragma unroll
    for (int nt = 0; nt < 2; ++nt) {
      float4 sc = Asc[par][nt];       // {cc, inv, q, inv*log2e}
      f32x4 d1 = __builtin_amdgcn_mfma_f32_16x16x32_fp8_fp8(az[0], Abc0[par][nt], zero, 0, 0, 0);
      d1       = __builtin_amdgcn_mfma_f32_16x16x32_fp8_fp8(az[1], Abc1[par][nt], d1,   0, 0, 0);
      f32x4 d2 = __builtin_amdgcn_mfma_f32_16x16x32_fp8_fp8(az[0], Abw0[par][nt], zero, 0, 0, 0);
      d2       = __builtin_amdgcn_mfma_f32_16x16x32_fp8_fp8(az[1], Abw1[par][nt], d2,   0, 0, 0);
#pragma unroll
      for (int i = 0; i < 4; ++i) {
        // e = (2*d1 - (zz+cc)) * inv * log2e, clamped <= 0; p = 2^e
        float e = fmaf(d1[i], 2.f, -(zzr[i] + sc.x)) * sc.w;
        e = fminf(e, 0.f);
        float p;
        asm("v_exp_f32 %0, %1" : "=v"(p) : "v"(e));
        dl[i] += p * sc.y * (d2[i] - sc.z);
        phs[pb + (quad * 4 + i) * PH_LD + nt * 16 + lrow] = f8_1(p);
      }
    }
    // ---- GEMM2: dz += phi @ Wz (pure-MFMA cluster -> setprio) ----
    long ap0 = *(const long*)&phs[pb + lrow * PH_LD + quad * 8];
    __builtin_amdgcn_s_setprio(1);
#pragma unroll
    for (int nt = 0; nt < 4; ++nt)
      acc[nt] = __builtin_amdgcn_mfma_f32_16x16x32_fp8_fp8(ap0, Abb[par][nt], acc[nt], 0, 0, 0);
    __builtin_amdgcn_s_setprio(0);
  }
#undef LOADB

  // ---- dl partials (dlr not unioned; safe before combine barriers) ----
#pragma unroll
  for (int i = 0; i < 4; ++i) {
    float v = dl[i];
    v += __shfl_xor(v, 1);
    v += __shfl_xor(v, 2);
    v += __shfl_xor(v, 4);
    v += __shfl_xor(v, 8);
    if (lrow == 0) dlr[ws][quad * 4 + i] = v;
  }

  // ---- dz combine across the 4 c-split waves (eps reuses phi LDS) ----
  for (int s = 0; s < 4; ++s) {
    __syncthreads();
    if (ws == s) {
#pragma unroll
      for (int nt = 0; nt < 4; ++nt)
#pragma unroll
        for (int i = 0; i < 4; ++i) {
          int r = quad * 4 + i;
          int d = nt * 16 + lrow;
          if (s == 0) eps[r * 68 + d] = acc[nt][i];
          else        eps[r * 68 + d] += acc[nt][i];
        }
    }
  }
  __syncthreads();

  // ---- outputs ----
  {
    int r = tid >> 4, d0 = (tid & 15) * 4;  // 256 thr x 4 floats = 16x64
    float4 e0 = *(const float4*)&eps[r * 68 + d0];
    float4 bv0 = *(const float4*)&bias[d0];
    float4 o0;
    o0.x = e0.x + bv0.x; o0.y = e0.y + bv0.y; o0.z = e0.z + bv0.z; o0.w = e0.w + bv0.w;
    *(float4*)&out[(size_t)(b0 + r) * DD + d0] = o0;
  }
  if (tid < 16) {
    float s = dlr[0][tid] + dlr[1][tid] + dlr[2][tid] + dlr[3][tid];
    out[(size_t)BB * DD + b0 + tid] = 2.f * s;
  }
}

// ---------------------------------------------------------------------------
extern "C" void kernel_launch(void* const* d_in, const int* in_sizes, int n_in,
                              void* d_out, int out_size, void* d_ws, size_t ws_size,
                              hipStream_t stream)
{
  const float* t   = (const float*)d_in[0];
  const float* z   = (const float*)d_in[1];
  // d_in[2] = logp_z (unused)
  const float* cz  = (const float*)d_in[3];
  const float* lsz = (const float*)d_in[4];
  const float* ct  = (const float*)d_in[5];
  const float* lst = (const float*)d_in[6];
  const float* W   = (const float*)d_in[7];
  float* out = (float*)d_out;
  float* ws  = (float*)d_ws;

  float*  bias = ws + BIAS_OFF;
  float4* scs  = (float4*)(ws + SCS_OFF);
  uchar*  cz8a = (uchar*)(ws + CZ8A_OFF);
  uchar*  cz8b = (uchar*)(ws + CZ8B_OFF);
  uchar*  wz8a = (uchar*)(ws + WZ8A_OFF);
  uchar*  wz8b = (uchar*)(ws + WZ8B_OFF);
  uchar*  wzbp8 = (uchar*)(ws + WZBP_OFF);
  float*  part = ws + PART_OFF;

  k_wt1<<<dim3(9, 64, 4), 256, 0, stream>>>(t, ct, lst, W, part);
  k_prep2<<<dim3(256), 256, 0, stream>>>(part, cz, lsz, bias, scs,
                                         cz8a, cz8b, wz8a, wz8b, wzbp8);
  k_fused<<<dim3(BB / 16), 256, 0, stream>>>(z, cz8a, cz8b,
                                             wz8a, wz8b, wzbp8, scs, bias, out);
}

// Round 5
// 137.785 us; speedup vs baseline: 2.0904x; 1.1467x over previous
//
#include <hip/hip_runtime.h>
#include <math.h>

typedef unsigned int uint;
typedef unsigned short ushort;
typedef unsigned char uchar;
typedef unsigned long ulong_;
typedef __attribute__((ext_vector_type(4))) float f32x4;

// Problem constants
#define BB  16384
#define DD  64
#define NT_ 128
#define NZ_ 2048
#define NJ_ 2049   // NZ+1

// workspace layout (float offsets)
#define BIAS_OFF 0         // fp32 [64]
#define SCS_OFF  64        // float4 [2048] = {cc, inv, q, inv*log2e}
#define CZ8A_OFF 8256      // fp8 cz k0 [NZ][32]
#define CZ8B_OFF 24640     // fp8 cz k1 [NZ][32]
#define WZ8A_OFF 41024     // fp8 WzT k0 [NZ][32]
#define WZ8B_OFF 57408     // fp8 WzT k1 [NZ][32]
#define WZBP_OFF 73792     // fp8 Wz packed [64 chunks][64 d][32 c]
#define PART_OFF 106560    // fp32 partials [4][64][NJ_] = 524544
// end 631104 floats ~= 2.5 MB

// ---------------- fp8 e4m3 (OCP) conversion helpers ----------------
#if __has_builtin(__builtin_amdgcn_cvt_pk_fp8_f32)
__device__ __forceinline__ uint pk4_fp8(float a, float b, float c, float d) {
  int v = __builtin_amdgcn_cvt_pk_fp8_f32(a, b, 0, false);
  v = __builtin_amdgcn_cvt_pk_fp8_f32(c, d, v, true);
  return (uint)v;
}
__device__ __forceinline__ uchar f8_1(float x) {
  return (uchar)(__builtin_amdgcn_cvt_pk_fp8_f32(x, x, 0, false) & 0xFF);
}
#else
__device__ __forceinline__ uint sw_f8(float x) {
  uint u = __float_as_uint(x);
  uint s = (u >> 24) & 0x80u;
  float ax = __uint_as_float(u & 0x7FFFFFFFu);
  if (!(ax >= 0.015625f)) return s;          // flush tiny / NaN -> signed zero
  if (ax >= 448.f) return s | 0x7Eu;
  uint q = __float_as_uint(ax);
  q += 0x7FFFFu + ((q >> 20) & 1u);          // RNE at mantissa bit 20
  uint e = (q >> 23) - 120u;                 // rebias (127 -> 7)
  return s | ((e & 0xFu) << 3) | ((q >> 20) & 7u);
}
__device__ __forceinline__ uchar f8_1(float x) { return (uchar)sw_f8(x); }
__device__ __forceinline__ uint pk4_fp8(float a, float b, float c, float d) {
  return sw_f8(a) | (sw_f8(b) << 8) | (sw_f8(c) << 16) | (sw_f8(d) << 24);
}
#endif

// ---------------------------------------------------------------------------
// Kernel 1 (stage 1): split-K partial sums of W_t = einsum('dij,i->dj').
// 2304 blocks (9/CU, 32 waves/CU) -> latency-tolerant W read (67 MB, BW-bound).
// R2 lesson: at 8 waves/CU this read pattern collapses to ~330 GB/s; keep the
// high block count.
__global__ __launch_bounds__(256) void k_wt1(
    const float* __restrict__ t, const float* __restrict__ ct,
    const float* __restrict__ lst, const float* __restrict__ W,
    float* __restrict__ part)   // [4][64][NJ_]
{
  __shared__ float ph[32];
  int tx = threadIdx.x;
  int d  = blockIdx.y;
  int ic = blockIdx.z;
  if (tx < 32) {
    int i = ic * 32 + tx;
    float r = fabsf(t[0] - ct[i]) * __expf(-lst[i]);
    ph[tx] = __expf(-r * r);
  }
  __syncthreads();
  int j = blockIdx.x * 256 + tx;
  if (j >= NJ_) return;
  const float* Wp = W + (size_t)d * NT_ * NJ_ + (size_t)(ic * 32) * NJ_ + j;
  float acc = 0.f;
#pragma unroll
  for (int k = 0; k < 32; ++k) acc += Wp[(size_t)k * NJ_] * ph[k];
  part[((size_t)ic * 64 + d) * NJ_ + j] = acc;
}

// ---------------------------------------------------------------------------
// Kernel 2 (stage 2): 256 blocks x 256 thr, 8 centres/block.
__global__ __launch_bounds__(256) void k_prep2(
    const float* __restrict__ part, const float* __restrict__ cz,
    const float* __restrict__ lsz,
    float* __restrict__ bias, float4* __restrict__ scs,
    uchar* __restrict__ cz8a, uchar* __restrict__ cz8b,
    uchar* __restrict__ wz8a, uchar* __restrict__ wz8b,
    uchar* __restrict__ wzbp8)
{
  __shared__ float wt[64][9];   // [d][c_local]
  int tid = threadIdx.x;
  int cb0 = blockIdx.x * 8;
#pragma unroll
  for (int h = 0; h < 2; ++h) {
    int f = h * 256 + tid;      // 512 = 64 d x 8 c
    int d = f >> 3, c = f & 7;
    size_t idx = (size_t)d * NJ_ + cb0 + c;
    float s = part[idx] + part[(size_t)64 * NJ_ + idx]
            + part[(size_t)128 * NJ_ + idx] + part[(size_t)192 * NJ_ + idx];
    wt[d][c] = s;
    int cg = cb0 + c;
    wzbp8[((size_t)(cg >> 5) * 64 + d) * 32 + (cg & 31)] = f8_1(s);
  }
  if (blockIdx.x == 0 && tid < 64) {
    size_t idx = (size_t)tid * NJ_ + 2048;
    bias[tid] = part[idx] + part[(size_t)64 * NJ_ + idx]
              + part[(size_t)128 * NJ_ + idx] + part[(size_t)192 * NJ_ + idx];
  }
  __syncthreads();
  int cl = tid >> 5;            // centre within block 0..7
  int k  = tid & 31;            // 0..31
  int c  = cb0 + cl;
  float cv0 = cz[(size_t)c * DD + k];
  float cv1 = cz[(size_t)c * DD + 32 + k];
  cz8a[(size_t)c * 32 + k] = f8_1(cv0);
  cz8b[(size_t)c * 32 + k] = f8_1(cv1);
  float w0 = wt[k][cl], w1 = wt[32 + k][cl];
  wz8a[(size_t)c * 32 + k] = f8_1(w0);
  wz8b[(size_t)c * 32 + k] = f8_1(w1);
  float ca = cv0 * cv0 + cv1 * cv1;
  float qa = w0 * cv0 + w1 * cv1;
  qa += __shfl_xor(qa, 1);  ca += __shfl_xor(ca, 1);
  qa += __shfl_xor(qa, 2);  ca += __shfl_xor(ca, 2);
  qa += __shfl_xor(qa, 4);  ca += __shfl_xor(ca, 4);
  qa += __shfl_xor(qa, 8);  ca += __shfl_xor(ca, 8);
  qa += __shfl_xor(qa, 16); ca += __shfl_xor(ca, 16);
  if (k == 0) {
    float inv = __expf(-2.f * lsz[c]);
    scs[c] = make_float4(ca, inv, qa, inv * 1.44269504f);
  }
}

// ---------------------------------------------------------------------------
// Main fused MFMA kernel — fp8, software-pipelined K-loop.
// BM=32, grid 512 (proven R1 config). R4 lesson: __launch_bounds__(256,4)
// made the backend allocate 64 VGPRs and spill the register double-buffer
// to scratch (11 MB of spill writes, k_fused 31->50 us). (256,2) pins the
// cap at 256 VGPR; the ~170-VGPR working set then stays in registers.
// Chunk schedule: GEMM1 MFMAs -> prefetch LOADB -> elementwise -> GEMM2, so
// every prefetch has the whole elementwise phase (~400 cyc) between issue
// and the next possible waitcnt -> L2 latency hidden, not exposed per chunk.
#define PH_LD 40   // bytes per phi row (32 + 8 pad)

__global__ __launch_bounds__(256, 2) void k_fused(
    const float* __restrict__ z,
    const uchar* __restrict__ cz8a, const uchar* __restrict__ cz8b,
    const uchar* __restrict__ wz8a, const uchar* __restrict__ wz8b,
    const uchar* __restrict__ wzbp8,
    const float4* __restrict__ scs, const float* __restrict__ bias,
    float* __restrict__ out)
{
  __shared__ char smem[10240];   // phi [2][4][32][PH_LD] fp8  OR  eps [32][68] f32
  __shared__ float dlr[4][32];
  uchar* phs = (uchar*)smem;
  float* eps = (float*)smem;

  int tid  = threadIdx.x;
  int ws   = tid >> 6;           // wave = c-split group 0..3
  int lane = tid & 63;
  int lrow = lane & 15, quad = lane >> 4;
  int b0 = blockIdx.x * 32;

  // ---- A-side prologue: read fp32 z rows, pack fp8 frags + row norms ----
  long az[2][2];
  float zzr[2][4];
#pragma unroll
  for (int mt = 0; mt < 2; ++mt) {
    const float* zr = z + (size_t)(b0 + mt * 16 + lrow) * DD + quad * 8;
    float4 v0 = *(const float4*)zr;
    float4 v1 = *(const float4*)(zr + 4);
    float4 v2 = *(const float4*)(zr + 32);
    float4 v3 = *(const float4*)(zr + 36);
    uint l0 = pk4_fp8(v0.x, v0.y, v0.z, v0.w);
    uint l1 = pk4_fp8(v1.x, v1.y, v1.z, v1.w);
    uint h0 = pk4_fp8(v2.x, v2.y, v2.z, v2.w);
    uint h1 = pk4_fp8(v3.x, v3.y, v3.z, v3.w);
    az[mt][0] = (long)(((ulong_)l1 << 32) | l0);
    az[mt][1] = (long)(((ulong_)h1 << 32) | h0);
    float ss = v0.x * v0.x + v0.y * v0.y + v0.z * v0.z + v0.w * v0.w
             + v1.x * v1.x + v1.y * v1.y + v1.z * v1.z + v1.w * v1.w
             + v2.x * v2.x + v2.y * v2.y + v2.z * v2.z + v2.w * v2.w
             + v3.x * v3.x + v3.y * v3.y + v3.z * v3.z + v3.w * v3.w;
    ss += __shfl_xor(ss, 16);    // combine the 4 quad partials per row
    ss += __shfl_xor(ss, 32);
#pragma unroll
    for (int i = 0; i < 4; ++i) zzr[mt][i] = __shfl(ss, quad * 4 + i);
  }

  f32x4 acc[2][4];
#pragma unroll
  for (int mt = 0; mt < 2; ++mt)
#pragma unroll
    for (int nt = 0; nt < 4; ++nt) acc[mt][nt] = (f32x4){0.f, 0.f, 0.f, 0.f};
  float dl[2][4] = {{0.f}};

  const f32x4 zero = (f32x4){0.f, 0.f, 0.f, 0.f};
  int cbase = ws * 512;
  int pbase = ws * 32 * PH_LD;   // within one parity bank

  // ---- register double-buffered prefetch state ----
  long Abc0[2][2], Abc1[2][2], Abw0[2][2], Abw1[2][2], Abb[2][4];
  float4 Asc[2][2];
#define LOADB(PAR, C0)                                                         \
  do {                                                                         \
    int c0_ = (C0);                                                            \
    _Pragma("unroll")                                                          \
    for (int nt = 0; nt < 2; ++nt) {                                           \
      int cg_ = c0_ + nt * 16 + lrow;                                          \
      size_t ro_ = (size_t)cg_ * 32 + quad * 8;                                \
      Abc0[PAR][nt] = *(const long*)(cz8a + ro_);                              \
      Abc1[PAR][nt] = *(const long*)(cz8b + ro_);                              \
      Abw0[PAR][nt] = *(const long*)(wz8a + ro_);                              \
      Abw1[PAR][nt] = *(const long*)(wz8b + ro_);                              \
      Asc[PAR][nt]  = scs[cg_];                                                \
    }                                                                          \
    size_t cb_ = (size_t)(c0_ >> 5) * 64 * 32;                                 \
    _Pragma("unroll")                                                          \
    for (int nt = 0; nt < 4; ++nt)                                             \
      Abb[PAR][nt] =                                                           \
          *(const long*)(wzbp8 + cb_ + (size_t)(nt * 16 + lrow) * 32 + quad * 8); \
  } while (0)

  LOADB(0, cbase);
#pragma unroll 2
  for (int it = 0; it < 16; ++it) {
    int par = it & 1;
    int pb = par * (4 * 32 * PH_LD) + pbase;

    // ---- GEMM1: all 16 MFMAs first (results held in registers) ----
    f32x4 d1a[2][2], d2a[2][2];
#pragma unroll
    for (int nt = 0; nt < 2; ++nt)
#pragma unroll
      for (int mt = 0; mt < 2; ++mt) {
        f32x4 d1 = __builtin_amdgcn_mfma_f32_16x16x32_fp8_fp8(az[mt][0], Abc0[par][nt], zero, 0, 0, 0);
        d1       = __builtin_amdgcn_mfma_f32_16x16x32_fp8_fp8(az[mt][1], Abc1[par][nt], d1,   0, 0, 0);
        f32x4 d2 = __builtin_amdgcn_mfma_f32_16x16x32_fp8_fp8(az[mt][0], Abw0[par][nt], zero, 0, 0, 0);
        d2       = __builtin_amdgcn_mfma_f32_16x16x32_fp8_fp8(az[mt][1], Abw1[par][nt], d2,   0, 0, 0);
        d1a[nt][mt] = d1;
        d2a[nt][mt] = d2;
      }

    // ---- prefetch next chunk NOW: elementwise below covers the L2 latency
    LOADB(par ^ 1, cbase + ((it + 1) & 15) * 32);

    // ---- elementwise: phi = exp2(clamped), dl accum, fp8 pack to LDS ----
#pragma unroll
    for (int nt = 0; nt < 2; ++nt) {
      float4 sc = Asc[par][nt];       // {cc, inv, q, inv*log2e}
#pragma unroll
      for (int mt = 0; mt < 2; ++mt) {
#pragma unroll
        for (int i = 0; i < 4; ++i) {
          float e = fmaf(d1a[nt][mt][i], 2.f, -(zzr[mt][i] + sc.x)) * sc.w;
          e = fminf(e, 0.f);
          float p;
          asm("v_exp_f32 %0, %1" : "=v"(p) : "v"(e));
          dl[mt][i] += p * sc.y * (d2a[nt][mt][i] - sc.z);
          phs[pb + (mt * 16 + quad * 4 + i) * PH_LD + nt * 16 + lrow] = f8_1(p);
        }
      }
    }

    // ---- GEMM2: dz += phi @ Wz (pure-MFMA cluster -> setprio) ----
    long ap0 = *(const long*)&phs[pb + lrow * PH_LD + quad * 8];
    long ap1 = *(const long*)&phs[pb + (16 + lrow) * PH_LD + quad * 8];
    __builtin_amdgcn_s_setprio(1);
#pragma unroll
    for (int nt = 0; nt < 4; ++nt) {
      acc[0][nt] = __builtin_amdgcn_mfma_f32_16x16x32_fp8_fp8(ap0, Abb[par][nt], acc[0][nt], 0, 0, 0);
      acc[1][nt] = __builtin_amdgcn_mfma_f32_16x16x32_fp8_fp8(ap1, Abb[par][nt], acc[1][nt], 0, 0, 0);
    }
    __builtin_amdgcn_s_setprio(0);
  }
#undef LOADB

  // ---- dl partials (dlr not unioned; safe before combine barriers) ----
#pragma unroll
  for (int mt = 0; mt < 2; ++mt)
#pragma unroll
    for (int i = 0; i < 4; ++i) {
      float v = dl[mt][i];
      v += __shfl_xor(v, 1);
      v += __shfl_xor(v, 2);
      v += __shfl_xor(v, 4);
      v += __shfl_xor(v, 8);
      if (lrow == 0) dlr[ws][mt * 16 + quad * 4 + i] = v;
    }

  // ---- dz combine across the 4 c-split waves (eps reuses phi LDS) ----
  for (int s = 0; s < 4; ++s) {
    __syncthreads();
    if (ws == s) {
#pragma unroll
      for (int mt = 0; mt < 2; ++mt)
#pragma unroll
        for (int nt = 0; nt < 4; ++nt)
#pragma unroll
          for (int i = 0; i < 4; ++i) {
            int r = mt * 16 + quad * 4 + i;
            int d = nt * 16 + lrow;
            if (s == 0) eps[r * 68 + d] = acc[mt][nt][i];
            else        eps[r * 68 + d] += acc[mt][nt][i];
          }
    }
  }
  __syncthreads();

  // ---- outputs ----
  {
    int r = tid >> 3, d0 = (tid & 7) * 8;   // 256 thr x 8 floats = 32x64
    float4 e0 = *(const float4*)&eps[r * 68 + d0];
    float4 e1 = *(const float4*)&eps[r * 68 + d0 + 4];
    float4 bv0 = *(const float4*)&bias[d0];
    float4 bv1 = *(const float4*)&bias[d0 + 4];
    float4 o0, o1;
    o0.x = e0.x + bv0.x; o0.y = e0.y + bv0.y; o0.z = e0.z + bv0.z; o0.w = e0.w + bv0.w;
    o1.x = e1.x + bv1.x; o1.y = e1.y + bv1.y; o1.z = e1.z + bv1.z; o1.w = e1.w + bv1.w;
    *(float4*)&out[(size_t)(b0 + r) * DD + d0]     = o0;
    *(float4*)&out[(size_t)(b0 + r) * DD + d0 + 4] = o1;
  }
  if (tid < 32) {
    float s = dlr[0][tid] + dlr[1][tid] + dlr[2][tid] + dlr[3][tid];
    out[(size_t)BB * DD + b0 + tid] = 2.f * s;
  }
}

// ---------------------------------------------------------------------------
extern "C" void kernel_launch(void* const* d_in, const int* in_sizes, int n_in,
                              void* d_out, int out_size, void* d_ws, size_t ws_size,
                              hipStream_t stream)
{
  const float* t   = (const float*)d_in[0];
  const float* z   = (const float*)d_in[1];
  // d_in[2] = logp_z (unused)
  const float* cz  = (const float*)d_in[3];
  const float* lsz = (const float*)d_in[4];
  const float* ct  = (const float*)d_in[5];
  const float* lst = (const float*)d_in[6];
  const float* W   = (const float*)d_in[7];
  float* out = (float*)d_out;
  float* ws  = (float*)d_ws;

  float*  bias = ws + BIAS_OFF;
  float4* scs  = (float4*)(ws + SCS_OFF);
  uchar*  cz8a = (uchar*)(ws + CZ8A_OFF);
  uchar*  cz8b = (uchar*)(ws + CZ8B_OFF);
  uchar*  wz8a = (uchar*)(ws + WZ8A_OFF);
  uchar*  wz8b = (uchar*)(ws + WZ8B_OFF);
  uchar*  wzbp8 = (uchar*)(ws + WZBP_OFF);
  float*  part = ws + PART_OFF;

  k_wt1<<<dim3(9, 64, 4), 256, 0, stream>>>(t, ct, lst, W, part);
  k_prep2<<<dim3(256), 256, 0, stream>>>(part, cz, lsz, bias, scs,
                                         cz8a, cz8b, wz8a, wz8b, wzbp8);
  k_fused<<<dim3(BB / 32), 256, 0, stream>>>(z, cz8a, cz8b,
                                             wz8a, wz8b, wzbp8, scs, bias, out);
}

// Round 7
// 137.550 us; speedup vs baseline: 2.0939x; 1.0017x over previous
//
#include <hip/hip_runtime.h>
#include <math.h>

typedef unsigned int uint;
typedef unsigned short ushort;
typedef unsigned char uchar;
typedef unsigned long ulong_;
typedef __attribute__((ext_vector_type(4))) float f32x4;

// Problem constants
#define BB  16384
#define DD  64
#define NT_ 128
#define NZ_ 2048
#define NJ_ 2049   // NZ+1

// workspace layout (float offsets) — ALL REGIONS DISJOINT (R6 bug: wzbp8 is
// 131072 BYTES = 32768 floats; PART_OFF was set as if it were 16384 floats,
// overlapping part[88128..104511] and racing k_prep2's wzbp8 writes against
// its part reads -> nondeterministic tripwire failure).
#define BIAS_OFF 0         // fp32 [64]                       -> end 64
#define IL2_OFF  64        // il2[c] = exp(-2 lsz)*log2e [2048] -> end 2112
#define A0_OFF   2112      // a0[c]  = -cc * il2         [2048] -> end 4160
#define NIQ_OFF  4160      // niq[c] = -inv * q          [2048] -> end 6208
#define CZ8A_OFF 6208      // fp8 cz k0 [NZ][32] = 16384 floats -> end 22592
#define CZ8B_OFF 22592     // fp8 cz k1                         -> end 38976
#define WZ8A_OFF 38976     // fp8 WzT k0                        -> end 55360
#define WZ8B_OFF 55360     // fp8 WzT k1                        -> end 71744
#define WZBP_OFF 71744     // fp8 Wz packed [64][64][32] B = 32768 floats -> end 104512
#define PART_OFF 104512    // fp32 partials [4][64][NJ_] = 524544 -> end 629056
// end 629056 floats ~= 2.52 MB

// ---------------- fp8 e4m3 (OCP) conversion helpers ----------------
#if __has_builtin(__builtin_amdgcn_cvt_pk_fp8_f32)
__device__ __forceinline__ uint pk4_fp8(float a, float b, float c, float d) {
  int v = __builtin_amdgcn_cvt_pk_fp8_f32(a, b, 0, false);
  v = __builtin_amdgcn_cvt_pk_fp8_f32(c, d, v, true);
  return (uint)v;
}
__device__ __forceinline__ uchar f8_1(float x) {
  return (uchar)(__builtin_amdgcn_cvt_pk_fp8_f32(x, x, 0, false) & 0xFF);
}
#else
__device__ __forceinline__ uint sw_f8(float x) {
  uint u = __float_as_uint(x);
  uint s = (u >> 24) & 0x80u;
  float ax = __uint_as_float(u & 0x7FFFFFFFu);
  if (!(ax >= 0.015625f)) return s;          // flush tiny / NaN -> signed zero
  if (ax >= 448.f) return s | 0x7Eu;
  uint q = __float_as_uint(ax);
  q += 0x7FFFFu + ((q >> 20) & 1u);          // RNE at mantissa bit 20
  uint e = (q >> 23) - 120u;                 // rebias (127 -> 7)
  return s | ((e & 0xFu) << 3) | ((q >> 20) & 7u);
}
__device__ __forceinline__ uchar f8_1(float x) { return (uchar)sw_f8(x); }
__device__ __forceinline__ uint pk4_fp8(float a, float b, float c, float d) {
  return sw_f8(a) | (sw_f8(b) << 8) | (sw_f8(c) << 16) | (sw_f8(d) << 24);
}
#endif

// ---------------------------------------------------------------------------
// Kernel 1 (stage 1): split-K partial sums of W_t = einsum('dij,i->dj').
// 2304 blocks (9/CU, 32 waves/CU) -> latency-tolerant W read (67 MB, BW-bound,
// near the 10.6us HBM floor). R2 lesson: at 8 waves/CU this same pattern
// collapses to ~330 GB/s; keep the high block count.
__global__ __launch_bounds__(256) void k_wt1(
    const float* __restrict__ t, const float* __restrict__ ct,
    const float* __restrict__ lst, const float* __restrict__ W,
    float* __restrict__ part)   // [4][64][NJ_]
{
  __shared__ float ph[32];
  int tx = threadIdx.x;
  int d  = blockIdx.y;
  int ic = blockIdx.z;
  if (tx < 32) {
    int i = ic * 32 + tx;
    float r = fabsf(t[0] - ct[i]) * __expf(-lst[i]);
    ph[tx] = __expf(-r * r);
  }
  __syncthreads();
  int j = blockIdx.x * 256 + tx;
  if (j >= NJ_) return;
  const float* Wp = W + (size_t)d * NT_ * NJ_ + (size_t)(ic * 32) * NJ_ + j;
  float acc = 0.f;
#pragma unroll
  for (int k = 0; k < 32; ++k) acc += Wp[(size_t)k * NJ_] * ph[k];
  part[((size_t)ic * 64 + d) * NJ_ + j] = acc;
}

// ---------------------------------------------------------------------------
// Kernel 2 (stage 2): 256 blocks x 256 thr, 8 centres/block.
// Emits PLANAR per-centre constants {il2, a0, niq}: the swapped-GEMM1 layout
// in k_fused indexes them along quad*4+i, so planar float4 loads are the
// cheap delivery.
__global__ __launch_bounds__(256) void k_prep2(
    const float* __restrict__ part, const float* __restrict__ cz,
    const float* __restrict__ lsz,
    float* __restrict__ bias,
    float* __restrict__ il2a, float* __restrict__ a0a, float* __restrict__ niqa,
    uchar* __restrict__ cz8a, uchar* __restrict__ cz8b,
    uchar* __restrict__ wz8a, uchar* __restrict__ wz8b,
    uchar* __restrict__ wzbp8)
{
  __shared__ float wt[64][9];   // [d][c_local]
  int tid = threadIdx.x;
  int cb0 = blockIdx.x * 8;
#pragma unroll
  for (int h = 0; h < 2; ++h) {
    int f = h * 256 + tid;      // 512 = 64 d x 8 c
    int d = f >> 3, c = f & 7;
    size_t idx = (size_t)d * NJ_ + cb0 + c;
    float s = part[idx] + part[(size_t)64 * NJ_ + idx]
            + part[(size_t)128 * NJ_ + idx] + part[(size_t)192 * NJ_ + idx];
    wt[d][c] = s;
    int cg = cb0 + c;
    wzbp8[((size_t)(cg >> 5) * 64 + d) * 32 + (cg & 31)] = f8_1(s);
  }
  if (blockIdx.x == 0 && tid < 64) {
    size_t idx = (size_t)tid * NJ_ + 2048;
    bias[tid] = part[idx] + part[(size_t)64 * NJ_ + idx]
              + part[(size_t)128 * NJ_ + idx] + part[(size_t)192 * NJ_ + idx];
  }
  __syncthreads();
  int cl = tid >> 5;            // centre within block 0..7
  int k  = tid & 31;            // 0..31
  int c  = cb0 + cl;
  float cv0 = cz[(size_t)c * DD + k];
  float cv1 = cz[(size_t)c * DD + 32 + k];
  cz8a[(size_t)c * 32 + k] = f8_1(cv0);
  cz8b[(size_t)c * 32 + k] = f8_1(cv1);
  float w0 = wt[k][cl], w1 = wt[32 + k][cl];
  wz8a[(size_t)c * 32 + k] = f8_1(w0);
  wz8b[(size_t)c * 32 + k] = f8_1(w1);
  float ca = cv0 * cv0 + cv1 * cv1;
  float qa = w0 * cv0 + w1 * cv1;
  qa += __shfl_xor(qa, 1);  ca += __shfl_xor(ca, 1);
  qa += __shfl_xor(qa, 2);  ca += __shfl_xor(ca, 2);
  qa += __shfl_xor(qa, 4);  ca += __shfl_xor(ca, 4);
  qa += __shfl_xor(qa, 8);  ca += __shfl_xor(ca, 8);
  qa += __shfl_xor(qa, 16); ca += __shfl_xor(ca, 16);
  if (k == 0) {
    float inv = __expf(-2.f * lsz[c]);
    float il2 = inv * 1.44269504f;     // inv * log2e
    il2a[c] = il2;
    a0a[c]  = -ca * il2;               // -cc * il2
    niqa[c] = -inv * qa;               // -inv * q
  }
}

// ---------------------------------------------------------------------------
// Main fused MFMA kernel — fp8, swapped-operand GEMM1 + in-wave shuffle
// transpose (no phi LDS round-trip).
//
// GEMM1 computes mfma(cz,z) / mfma(Wz,z) so the C-layout puts each thread on
// its OWN z-row (lrow) at c = c0+nt*16+quad*4+i. The phi -> GEMM2-A-frag
// reshape is then a pure in-wave transpose: 8 shfl + 4 cndmask, replacing the
// old 16 ds_write_b8 + 2 ds_read_b64 + lgkmcnt(0) drain per chunk (the R5
// serialization point; SQ_LDS_BANK_CONFLICT 147456 = exactly 1/LDS-op).
// A/B fragment layouts are lane-transposes of each other, so az/Abc/Abw
// loads are bit-identical to R5 — only the mfma operand order changed.
// (256,2): R4 lesson — higher min-waves makes the backend spill (64 VGPR,
// 11 MB scratch traffic); cap at 2 blocks/CU, ~190 VGPR working set.
__global__ __launch_bounds__(256, 2) void k_fused(
    const float* __restrict__ z,
    const uchar* __restrict__ cz8a, const uchar* __restrict__ cz8b,
    const uchar* __restrict__ wz8a, const uchar* __restrict__ wz8b,
    const uchar* __restrict__ wzbp8,
    const float* __restrict__ il2a, const float* __restrict__ a0a,
    const float* __restrict__ niqa,
    const float* __restrict__ bias, float* __restrict__ out)
{
  __shared__ float eps[32 * 68];   // dz combine scratch (only LDS use now)
  __shared__ float dlr[4][32];

  int tid  = threadIdx.x;
  int ws   = tid >> 6;           // wave = c-split group 0..3
  int lane = tid & 63;
  int lrow = lane & 15, quad = lane >> 4;
  int b0 = blockIdx.x * 32;

  // ---- prologue: read fp32 z rows, pack fp8 frags + own-row norms ----
  long az[2][2];
  float nzz[2];
#pragma unroll
  for (int mt = 0; mt < 2; ++mt) {
    const float* zr = z + (size_t)(b0 + mt * 16 + lrow) * DD + quad * 8;
    float4 v0 = *(const float4*)zr;
    float4 v1 = *(const float4*)(zr + 4);
    float4 v2 = *(const float4*)(zr + 32);
    float4 v3 = *(const float4*)(zr + 36);
    uint l0 = pk4_fp8(v0.x, v0.y, v0.z, v0.w);
    uint l1 = pk4_fp8(v1.x, v1.y, v1.z, v1.w);
    uint h0 = pk4_fp8(v2.x, v2.y, v2.z, v2.w);
    uint h1 = pk4_fp8(v3.x, v3.y, v3.z, v3.w);
    az[mt][0] = (long)(((ulong_)l1 << 32) | l0);
    az[mt][1] = (long)(((ulong_)h1 << 32) | h0);
    float ss = v0.x * v0.x + v0.y * v0.y + v0.z * v0.z + v0.w * v0.w
             + v1.x * v1.x + v1.y * v1.y + v1.z * v1.z + v1.w * v1.w
             + v2.x * v2.x + v2.y * v2.y + v2.z * v2.z + v2.w * v2.w
             + v3.x * v3.x + v3.y * v3.y + v3.z * v3.z + v3.w * v3.w;
    ss += __shfl_xor(ss, 16);    // combine the 4 quad partials -> full row sum
    ss += __shfl_xor(ss, 32);
    nzz[mt] = -ss;               // own row's -|z|^2 (no broadcast needed)
  }

  f32x4 acc[2][4];
#pragma unroll
  for (int mt = 0; mt < 2; ++mt)
#pragma unroll
    for (int nt = 0; nt < 4; ++nt) acc[mt][nt] = (f32x4){0.f, 0.f, 0.f, 0.f};
  float dl[2] = {0.f, 0.f};

  const f32x4 zero = (f32x4){0.f, 0.f, 0.f, 0.f};
  int cbase = ws * 512;

  // ---- register double-buffered prefetch state (fp8 frags only) ----
  long Abc0[2][2], Abc1[2][2], Abw0[2][2], Abw1[2][2], Abb[2][4];
#define LOADB(PAR, C0)                                                         \
  do {                                                                         \
    int c0_ = (C0);                                                            \
    _Pragma("unroll")                                                          \
    for (int nt = 0; nt < 2; ++nt) {                                           \
      int cg_ = c0_ + nt * 16 + lrow;                                          \
      size_t ro_ = (size_t)cg_ * 32 + quad * 8;                                \
      Abc0[PAR][nt] = *(const long*)(cz8a + ro_);                              \
      Abc1[PAR][nt] = *(const long*)(cz8b + ro_);                              \
      Abw0[PAR][nt] = *(const long*)(wz8a + ro_);                              \
      Abw1[PAR][nt] = *(const long*)(wz8b + ro_);                              \
    }                                                                          \
    size_t cb_ = (size_t)(c0_ >> 5) * 64 * 32;                                 \
    _Pragma("unroll")                                                          \
    for (int nt = 0; nt < 4; ++nt)                                             \
      Abb[PAR][nt] =                                                           \
          *(const long*)(wzbp8 + cb_ + (size_t)(nt * 16 + lrow) * 32 + quad * 8); \
  } while (0)

  LOADB(0, cbase);
#pragma unroll 2
  for (int it = 0; it < 16; ++it) {
    int par = it & 1;
    int c0  = cbase + it * 32;

    // current-chunk planar constants; consumed after GEMM1 (latency covered)
    float4 ilv[2], a0v[2], nqv[2];
#pragma unroll
    for (int nt = 0; nt < 2; ++nt) {
      int cb = c0 + nt * 16 + quad * 4;
      ilv[nt] = *(const float4*)&il2a[cb];
      a0v[nt] = *(const float4*)&a0a[cb];
      nqv[nt] = *(const float4*)&niqa[cb];
    }

    // ---- GEMM1 (swapped): D[c_local][r_local]; thread owns row lrow ----
    f32x4 d1a[2][2], d2a[2][2];
#pragma unroll
    for (int nt = 0; nt < 2; ++nt)
#pragma unroll
      for (int mt = 0; mt < 2; ++mt) {
        f32x4 d1 = __builtin_amdgcn_mfma_f32_16x16x32_fp8_fp8(Abc0[par][nt], az[mt][0], zero, 0, 0, 0);
        d1       = __builtin_amdgcn_mfma_f32_16x16x32_fp8_fp8(Abc1[par][nt], az[mt][1], d1,   0, 0, 0);
        f32x4 d2 = __builtin_amdgcn_mfma_f32_16x16x32_fp8_fp8(Abw0[par][nt], az[mt][0], zero, 0, 0, 0);
        d2       = __builtin_amdgcn_mfma_f32_16x16x32_fp8_fp8(Abw1[par][nt], az[mt][1], d2,   0, 0, 0);
        d1a[nt][mt] = d1;
        d2a[nt][mt] = d2;
      }

    // ---- prefetch next chunk: elementwise below covers the L2 latency ----
    LOADB(par ^ 1, cbase + ((it + 1) & 15) * 32);

    // ---- elementwise: p = exp2(clamped), dl accum, pack 4 p's -> uint ----
    // element (mt,nt,i): r = b0+mt*16+lrow, c = c0+nt*16+quad*4+i
    uint u00, u01, u10, u11;
#pragma unroll
    for (int mt = 0; mt < 2; ++mt)
#pragma unroll
      for (int nt = 0; nt < 2; ++nt) {
        float pv[4];
#pragma unroll
        for (int i = 0; i < 4; ++i) {
          float il2 = ilv[nt][i];
          float t2  = d1a[nt][mt][i] + d1a[nt][mt][i];
          float uu  = fmaf(il2, nzz[mt], a0v[nt][i]);   // -(zz+cc)*il2
          float e   = fmaf(t2, il2, uu);                // (2 d1 - zz - cc)*il2
          e = fminf(e, 0.f);
          float p;
          asm("v_exp_f32 %0, %1" : "=v"(p) : "v"(e));   // exp2
          float g = fmaf(d2a[nt][mt][i] * 0.69314718f, il2, nqv[nt][i]); // inv*d2 - inv*q
          dl[mt] = fmaf(p, g, dl[mt]);
          pv[i] = p;
        }
        uint uv = pk4_fp8(pv[0], pv[1], pv[2], pv[3]);
        if (mt == 0) { if (nt == 0) u00 = uv; else u01 = uv; }
        else         { if (nt == 0) u10 = uv; else u11 = uv; }
      }

    // ---- in-wave transpose: phi (own-row layout) -> GEMM2 A-fragments ----
    // target lane (lrow,q) needs phi[row][q*8..q*8+7]; sources are quads
    // 2(q&1), 2(q&1)+1 of tile nt = q>>1.
    int  sl = lrow + ((lane & 16) << 1);   // lrow + 32*(q&1)
    bool hh = lane >= 32;                  // nt = q>>1
    uint l0a = __shfl(u00, sl),      l1a = __shfl(u01, sl);
    uint h0a = __shfl(u00, sl + 16), h1a = __shfl(u01, sl + 16);
    uint lo0 = hh ? l1a : l0a,       hi0 = hh ? h1a : h0a;
    long ap0 = (long)(((ulong_)hi0 << 32) | lo0);
    uint l0b = __shfl(u10, sl),      l1b = __shfl(u11, sl);
    uint h0b = __shfl(u10, sl + 16), h1b = __shfl(u11, sl + 16);
    uint lo1 = hh ? l1b : l0b,       hi1 = hh ? h1b : h0b;
    long ap1 = (long)(((ulong_)hi1 << 32) | lo1);

    // ---- GEMM2: dz += phi @ Wz (pure-MFMA cluster -> setprio) ----
    __builtin_amdgcn_s_setprio(1);
#pragma unroll
    for (int nt = 0; nt < 4; ++nt) {
      acc[0][nt] = __builtin_amdgcn_mfma_f32_16x16x32_fp8_fp8(ap0, Abb[par][nt], acc[0][nt], 0, 0, 0);
      acc[1][nt] = __builtin_amdgcn_mfma_f32_16x16x32_fp8_fp8(ap1, Abb[par][nt], acc[1][nt], 0, 0, 0);
    }
    __builtin_amdgcn_s_setprio(0);
  }
#undef LOADB

  // ---- dl partials: sum over the 4 quads holding the same row ----
#pragma unroll
  for (int mt = 0; mt < 2; ++mt) {
    float v = dl[mt];
    v += __shfl_xor(v, 16);
    v += __shfl_xor(v, 32);
    if (quad == 0) dlr[ws][mt * 16 + lrow] = v;
  }

  // ---- dz combine across the 4 c-split waves ----
  for (int s = 0; s < 4; ++s) {
    __syncthreads();
    if (ws == s) {
#pragma unroll
      for (int mt = 0; mt < 2; ++mt)
#pragma unroll
        for (int nt = 0; nt < 4; ++nt)
#pragma unroll
          for (int i = 0; i < 4; ++i) {
            int r = mt * 16 + quad * 4 + i;
            int d = nt * 16 + lrow;
            if (s == 0) eps[r * 68 + d] = acc[mt][nt][i];
            else        eps[r * 68 + d] += acc[mt][nt][i];
          }
    }
  }
  __syncthreads();

  // ---- outputs ----
  {
    int r = tid >> 3, d0 = (tid & 7) * 8;   // 256 thr x 8 floats = 32x64
    float4 e0 = *(const float4*)&eps[r * 68 + d0];
    float4 e1 = *(const float4*)&eps[r * 68 + d0 + 4];
    float4 bv0 = *(const float4*)&bias[d0];
    float4 bv1 = *(const float4*)&bias[d0 + 4];
    float4 o0, o1;
    o0.x = e0.x + bv0.x; o0.y = e0.y + bv0.y; o0.z = e0.z + bv0.z; o0.w = e0.w + bv0.w;
    o1.x = e1.x + bv1.x; o1.y = e1.y + bv1.y; o1.z = e1.z + bv1.z; o1.w = e1.w + bv1.w;
    *(float4*)&out[(size_t)(b0 + r) * DD + d0]     = o0;
    *(float4*)&out[(size_t)(b0 + r) * DD + d0 + 4] = o1;
  }
  if (tid < 32) {
    float s = dlr[0][tid] + dlr[1][tid] + dlr[2][tid] + dlr[3][tid];
    out[(size_t)BB * DD + b0 + tid] = 2.f * s;
  }
}

// ---------------------------------------------------------------------------
extern "C" void kernel_launch(void* const* d_in, const int* in_sizes, int n_in,
                              void* d_out, int out_size, void* d_ws, size_t ws_size,
                              hipStream_t stream)
{
  const float* t   = (const float*)d_in[0];
  const float* z   = (const float*)d_in[1];
  // d_in[2] = logp_z (unused)
  const float* cz  = (const float*)d_in[3];
  const float* lsz = (const float*)d_in[4];
  const float* ct  = (const float*)d_in[5];
  const float* lst = (const float*)d_in[6];
  const float* W   = (const float*)d_in[7];
  float* out = (float*)d_out;
  float* ws  = (float*)d_ws;

  float*  bias = ws + BIAS_OFF;
  float*  il2a = ws + IL2_OFF;
  float*  a0a  = ws + A0_OFF;
  float*  niqa = ws + NIQ_OFF;
  uchar*  cz8a = (uchar*)(ws + CZ8A_OFF);
  uchar*  cz8b = (uchar*)(ws + CZ8B_OFF);
  uchar*  wz8a = (uchar*)(ws + WZ8A_OFF);
  uchar*  wz8b = (uchar*)(ws + WZ8B_OFF);
  uchar*  wzbp8 = (uchar*)(ws + WZBP_OFF);
  float*  part = ws + PART_OFF;

  k_wt1<<<dim3(9, 64, 4), 256, 0, stream>>>(t, ct, lst, W, part);
  k_prep2<<<dim3(256), 256, 0, stream>>>(part, cz, lsz, bias,
                                         il2a, a0a, niqa,
                                         cz8a, cz8b, wz8a, wz8b, wzbp8);
  k_fused<<<dim3(BB / 32), 256, 0, stream>>>(z, cz8a, cz8b,
                                             wz8a, wz8b, wzbp8,
                                             il2a, a0a, niqa, bias, out);
}